// Round 5
// baseline (283.384 us; speedup 1.0000x reference)
//
#include <hip/hip_runtime.h>
#include <hip/hip_bf16.h>

#define WIDTH   128
#define NNODES  50000
#define NEDGES  640000
#define NTILES  3125          // 50000 / 16
#define TILES_PER_BLOCK 4     // 782 blocks; wave-pair does TPB/2 tiles each
#define WLDS_STRIDE 264       // 256 + 8 shorts pad

// binning: 32 node-ranges x 8 edge-segments, per-(node,segment) capacity 16
#define RBLK    32
#define SSEG    8
#define RSZ     1563          // ceil(50000/32)
#define SEG_EDGES 80000       // 640000/8
#define C0      16
#define CAPB    128           // slots per node = SSEG*C0

typedef __attribute__((ext_vector_type(8))) short  short8;
typedef __attribute__((ext_vector_type(4))) short  short4_t;
typedef __attribute__((ext_vector_type(4))) float  float4_t;

__device__ inline short f2bf(float f) {
    union { float f; unsigned int u; } a;
    a.f = f;
    unsigned int r = a.u + 0x7FFFu + ((a.u >> 16) & 1u);  // RNE
    return (short)(r >> 16);
}
__device__ inline unsigned int pack2bf(float a, float b) {
    unsigned int lo = (unsigned short)f2bf(a);
    unsigned int hi = (unsigned short)f2bf(b);
    return lo | (hi << 16);
}
__device__ inline float bflo(unsigned int u) { return __uint_as_float(u << 16); }
__device__ inline float bfhi(unsigned int u) { return __uint_as_float(u & 0xFFFF0000u); }

// ---------------------------------------------------------------------------
// Kernel 0: x fp32 -> xb bf16 (packed).
// ---------------------------------------------------------------------------
__global__ __launch_bounds__(256) void convert_kernel(
    const float* __restrict__ x, uint2* __restrict__ xb2)
{
    int i = blockIdx.x * 256 + threadIdx.x;           // 0 .. 1,599,999
    float4 v = *(const float4*)(x + (size_t)i * 4);
    uint2 p;
    p.x = pack2bf(v.x, v.y);
    p.y = pack2bf(v.z, v.w);
    xb2[i] = p;
}

// ---------------------------------------------------------------------------
// Kernel 1: bin edges by dst with LDS counters — NO global atomics.
// Block (r,s): streams segment s's dst slice, keeps edges whose dst falls in
// range r, takes position from LDS atomicAdd, writes src into the private
// sub-slot region buckets[dst*128 + s*16 + pos].  Per-(node,segment) counts
// written wholesale (no pre-zero needed).
// ---------------------------------------------------------------------------
__global__ __launch_bounds__(256) void bin_kernel(
    const int* __restrict__ e, int* __restrict__ counts2, int* __restrict__ buckets)
{
    __shared__ int cnt[RSZ];
    int r = blockIdx.x & (RBLK - 1);
    int s = blockIdx.x / RBLK;
    int base = r * RSZ;
    int rsz  = NNODES - base; if (rsz > RSZ) rsz = RSZ;

    for (int i = threadIdx.x; i < RSZ; i += 256) cnt[i] = 0;
    __syncthreads();

    int e0 = s * SEG_EDGES, e1 = e0 + SEG_EDGES;
    for (int i = e0 + threadIdx.x; i < e1; i += 256) {
        int dst = e[NEDGES + i];
        unsigned d = (unsigned)(dst - base);
        if (d < (unsigned)rsz) {
            int pos = atomicAdd(&cnt[d], 1);
            if (pos < C0) {
                int src = e[i];
                buckets[dst * CAPB + s * C0 + pos] = src;
            }
        }
    }
    __syncthreads();
    for (int i = threadIdx.x; i < rsz; i += 256) {
        int c = cnt[i]; if (c > C0) c = C0;
        counts2[(base + i) * SSEG + s] = c;
    }
}

// ---------------------------------------------------------------------------
// Kernel 2: one wave per node.  Prologue compacts the node's <=128 sub-slots
// into a dense src list in lanes [0,deg) via ballot+mbcnt+ds_permute.
// Main loop: lanes 0-31 gather edge j, lanes 32-63 edge j+1 (4 bf16
// channels/lane as uint2); 16 edges per unrolled block; idempotent-min tail
// clamp; cross-half shfl_xor(32) combine; lanes 0-31 store packed bf16.
// ---------------------------------------------------------------------------
__global__ __launch_bounds__(256) void gather_min_bf16_kernel(
    const uint2* __restrict__ xb2, const int* __restrict__ counts2,
    const int* __restrict__ buckets, uint2* __restrict__ maxes2)
{
    int wave = (blockIdx.x * 256 + threadIdx.x) >> 6;
    int lane = threadIdx.x & 63;
    if (wave >= NNODES) return;
    int node = wave;

    // ---- compaction prologue ----
    int s0 = lane >> 4;                   // 0..3
    int j  = lane & 15;
    int c0 = counts2[node * SSEG + s0];
    int c1 = counts2[node * SSEG + 4 + s0];
    int idx0 = buckets[node * CAPB + lane];
    int idx1 = buckets[node * CAPB + 64 + lane];
    bool v0 = j < c0;
    bool v1 = j < c1;
    unsigned long long m0 = __ballot(v0);
    unsigned long long m1 = __ballot(v1);
    int p0 = __builtin_amdgcn_mbcnt_hi((unsigned)(m0 >> 32),
             __builtin_amdgcn_mbcnt_lo((unsigned)m0, 0));
    int popc0 = __popcll(m0);
    int p1 = popc0 + __builtin_amdgcn_mbcnt_hi((unsigned)(m1 >> 32),
                     __builtin_amdgcn_mbcnt_lo((unsigned)m1, 0));
    int deg = popc0 + __popcll(m1);       // true degree (<= ~40 << 63)
    int t0 = v0 ? p0 : 63;                // invalid lanes dump to lane 63
    int t1 = v1 ? p1 : 63;
    int r0 = __builtin_amdgcn_ds_permute(t0 << 2, idx0);
    int r1 = __builtin_amdgcn_ds_permute(t1 << 2, idx1);
    int myidx = (lane < popc0) ? r0 : r1; // dense src list in lanes [0,deg)

    int h  = lane >> 5;        // which edge of the pair
    int cl = lane & 31;        // uint2 index within the row (4 channels)

    float4 m; m.x = 3.4e38f; m.y = 3.4e38f; m.z = 3.4e38f; m.w = 3.4e38f;
#pragma unroll 1
    for (int j0 = 0; j0 < deg; j0 += 16) {
        uint2 v[8];
#pragma unroll
        for (int u = 0; u < 8; ++u) {
            int jc = j0 + 2 * u + h;
            jc = jc < deg ? jc : deg - 1;          // idempotent-min tail clamp
            int src = __shfl(myidx, jc);
            v[u] = xb2[(size_t)src * 32 + cl];
        }
#pragma unroll
        for (int u = 0; u < 8; ++u) {
            m.x = fminf(m.x, bflo(v[u].x));
            m.y = fminf(m.y, bfhi(v[u].x));
            m.z = fminf(m.z, bflo(v[u].y));
            m.w = fminf(m.w, bfhi(v[u].y));
        }
    }
    m.x = fminf(m.x, __shfl_xor(m.x, 32));
    m.y = fminf(m.y, __shfl_xor(m.y, 32));
    m.z = fminf(m.z, __shfl_xor(m.z, 32));
    m.w = fminf(m.w, __shfl_xor(m.w, 32));

    if (h == 0) {
        uint2 o;
        if (deg > 0) {
            uint2 xv = xb2[(size_t)node * 32 + cl];
            o.x = pack2bf(bflo(xv.x) - m.x, bfhi(xv.x) - m.y);
            o.y = pack2bf(bflo(xv.y) - m.z, bfhi(xv.y) - m.w);
        } else {
            o.x = 0u; o.y = 0u;
        }
        maxes2[(size_t)node * 32 + cl] = o;
    }
}

// ---------------------------------------------------------------------------
// Fallback kernels (small-ws path): R4 versions.
// ---------------------------------------------------------------------------
__global__ __launch_bounds__(256) void fill_kernel(
    const int* __restrict__ e, int* __restrict__ counts, int* __restrict__ buckets)
{
    int i = blockIdx.x * 256 + threadIdx.x;
    if (i >= NEDGES) return;
    int src = e[i];
    int dst = e[NEDGES + i];
    int pos = atomicAdd(&counts[dst], 1);
    if (pos < 64) buckets[dst * 64 + pos] = src;
}

__global__ __launch_bounds__(256) void gather_min_fp32_kernel(
    const float* __restrict__ x, const int* __restrict__ counts,
    const int* __restrict__ buckets, unsigned int* __restrict__ maxes_u32)
{
    int wave = (blockIdx.x * 256 + threadIdx.x) >> 6;
    int lane = threadIdx.x & 63;
    if (wave >= NNODES) return;
    int node = wave;
    int deg  = counts[node];
    deg = deg > 64 ? 64 : deg;

    int myidx = (lane < deg) ? buckets[node * 64 + lane] : 0;
    int c = lane * 2;
    float2 m; m.x = 3.4e38f; m.y = 3.4e38f;
#pragma unroll 1
    for (int j0 = 0; j0 < deg; j0 += 8) {
        float2 v[8];
#pragma unroll
        for (int u = 0; u < 8; ++u) {
            int jc = j0 + u;
            jc = jc < deg ? jc : deg - 1;
            int src = __shfl(myidx, jc);
            v[u] = *(const float2*)(x + (size_t)src * WIDTH + c);
        }
#pragma unroll
        for (int u = 0; u < 8; ++u) {
            m.x = fminf(m.x, v[u].x);
            m.y = fminf(m.y, v[u].y);
        }
    }
    float2 o;
    if (deg > 0) {
        float2 xv = *(const float2*)(x + (size_t)node * WIDTH + c);
        o.x = xv.x - m.x;
        o.y = xv.y - m.y;
    } else { o.x = 0.f; o.y = 0.f; }
    maxes_u32[(size_t)node * 64 + lane] = pack2bf(o.x, o.y);
}

// ---------------------------------------------------------------------------
// Kernel 3: fused  out = x + relu( [x, maxes] @ W^T + b ), bf16 MFMA.
// XB=true: A first half loads pre-converted bf16 x directly.
// ---------------------------------------------------------------------------
template<bool XB>
__global__ __launch_bounds__(256, 2) void fused_gemm_kernel(
    const float* __restrict__ x, const short* __restrict__ xb,
    const short* __restrict__ maxes,
    const float* __restrict__ W, const float* __restrict__ b,
    float* __restrict__ out)
{
    __shared__ short Wlds[WIDTH * WLDS_STRIDE];   // [n][k] bf16, padded

    const int t = threadIdx.x;

    // ---- stage W (128x256 fp32) -> LDS bf16 ----
#pragma unroll
    for (int i = 0; i < 32; ++i) {
        int idx4 = t + i * 256;
        int flat = idx4 << 2;
        float4 w = *(const float4*)(W + flat);
        int n = flat >> 8;
        int k = flat & 255;
        short4_t s;
        s.x = f2bf(w.x); s.y = f2bf(w.y); s.z = f2bf(w.z); s.w = f2bf(w.w);
        *(short4_t*)&Wlds[n * WLDS_STRIDE + k] = s;
    }
    __syncthreads();

    const int wave  = t >> 6;
    const int lane  = t & 63;
    const int lm    = lane & 15;
    const int quad  = lane >> 4;
    const int nhalf = wave & 1;
    const int wpair = wave >> 1;
    const int ncol_base = nhalf * 64;

    short8 bfrag[4][8];
#pragma unroll
    for (int nt = 0; nt < 4; ++nt) {
        int n = ncol_base + nt * 16 + lm;
#pragma unroll
        for (int kt = 0; kt < 8; ++kt) {
            int k = kt * 32 + quad * 8;
            bfrag[nt][kt] = *(const short8*)&Wlds[n * WLDS_STRIDE + k];
        }
    }

    const int tile0 = blockIdx.x * TILES_PER_BLOCK;
#pragma unroll 1
    for (int i = 0; i < TILES_PER_BLOCK / 2; ++i) {
        int tile = tile0 + 2 * i + wpair;
        if (tile >= NTILES) break;
        int row = tile * 16 + lm;
        const float* xr  = x     + (size_t)row * WIDTH;
        const short* xbr = XB ? (xb + (size_t)row * WIDTH) : nullptr;
        const short* mr  = maxes + (size_t)row * WIDTH;

        float4_t acc[4];
#pragma unroll
        for (int nt = 0; nt < 4; ++nt) { acc[nt].x = 0.f; acc[nt].y = 0.f; acc[nt].z = 0.f; acc[nt].w = 0.f; }

#pragma unroll
        for (int kt = 0; kt < 8; ++kt) {
            int k = kt * 32 + quad * 8;
            short8 afrag;
            if (k < WIDTH) {
                if (XB) {
                    afrag = *(const short8*)(xbr + k);
                } else {
                    float4 v0 = *(const float4*)(xr + k);
                    float4 v1 = *(const float4*)(xr + k + 4);
                    afrag[0] = f2bf(v0.x); afrag[1] = f2bf(v0.y);
                    afrag[2] = f2bf(v0.z); afrag[3] = f2bf(v0.w);
                    afrag[4] = f2bf(v1.x); afrag[5] = f2bf(v1.y);
                    afrag[6] = f2bf(v1.z); afrag[7] = f2bf(v1.w);
                }
            } else {
                afrag = *(const short8*)(mr + (k - WIDTH));
            }
#pragma unroll
            for (int nt = 0; nt < 4; ++nt) {
                acc[nt] = __builtin_amdgcn_mfma_f32_16x16x32_bf16(
                    afrag, bfrag[nt][kt], acc[nt], 0, 0, 0);
            }
        }

#pragma unroll
        for (int nt = 0; nt < 4; ++nt) {
            int col = ncol_base + nt * 16 + lm;
            float bias = b[col];
#pragma unroll
            for (int r = 0; r < 4; ++r) {
                int orow = tile * 16 + quad * 4 + r;
                float v = acc[nt][r] + bias;
                v = v > 0.f ? v : 0.f;
                size_t off = (size_t)orow * WIDTH + col;
                out[off] = x[off] + v;
            }
        }
    }
}

extern "C" void kernel_launch(void* const* d_in, const int* in_sizes, int n_in,
                              void* d_out, int out_size, void* d_ws, size_t ws_size,
                              hipStream_t stream) {
    const float* x = (const float*)d_in[0];
    const int*   e = (const int*)  d_in[1];
    const float* W = (const float*)d_in[2];
    const float* b = (const float*)d_in[3];
    float* out = (float*)d_out;

    char* ws = (char*)d_ws;
    int gemm_blocks = (NTILES + TILES_PER_BLOCK - 1) / TILES_PER_BLOCK;  // 782

    // main path workspace: counts2 (1.6MB) | buckets (25.6MB) | maxes (12.8MB) | xb (12.8MB)
    const size_t off_buckets = 1600000;
    const size_t off_maxes   = off_buckets + (size_t)NNODES * CAPB * 4;  // 27,200,000
    const size_t off_xb      = off_maxes + 12800000;                     // 40,000,000
    const size_t need        = off_xb + 12800000;                        // 52.8 MB

    if (ws_size >= need) {
        int*          counts2 = (int*)ws;
        int*          buckets = (int*)(ws + off_buckets);
        unsigned int* maxes   = (unsigned int*)(ws + off_maxes);
        short*        xb      = (short*)(ws + off_xb);

        convert_kernel<<<6250, 256, 0, stream>>>(x, (uint2*)xb);
        bin_kernel<<<RBLK * SSEG, 256, 0, stream>>>(e, counts2, buckets);
        gather_min_bf16_kernel<<<(NNODES + 3) / 4, 256, 0, stream>>>(
            (const uint2*)xb, counts2, buckets, (uint2*)maxes);
        fused_gemm_kernel<true><<<gemm_blocks, 256, 0, stream>>>(
            x, xb, (const short*)maxes, W, b, out);
    } else {
        // fallback: R4 path (global-atomic fill, fp32 gather)
        int*          counts  = (int*)ws;                            // 256 KB
        int*          buckets = (int*)(ws + 262144);                 // 12.8 MB
        unsigned int* maxes   = (unsigned int*)(ws + 262144 + 12800000);

        hipMemsetAsync(counts, 0, 262144, stream);
        fill_kernel<<<(NEDGES + 255) / 256, 256, 0, stream>>>(e, counts, buckets);
        gather_min_fp32_kernel<<<(NNODES + 3) / 4, 256, 0, stream>>>(
            x, counts, buckets, maxes);
        fused_gemm_kernel<false><<<gemm_blocks, 256, 0, stream>>>(
            x, nullptr, (const short*)maxes, W, b, out);
    }
}

// Round 6
// 143.997 us; speedup vs baseline: 1.9680x; 1.9680x over previous
//
#include <hip/hip_runtime.h>
#include <hip/hip_bf16.h>

#define WIDTH   128
#define NNODES  50000
#define NEDGES  640000
#define NTILES  3125          // 50000 / 16
#define WLDS_STRIDE 264       // 256 + 8 shorts pad (0 measured conflicts)

// binning: 32 node-ranges x 8 edge-segments, per-(node,segment) capacity 16
#define RBLK    32
#define SSEG    8
#define RSZ     1563          // ceil(50000/32)
#define SEG_I4  20000         // int4s per 80000-edge segment
#define C0      16
#define CAPB    128           // slots per node = SSEG*C0

#define BIN_BLOCKS  (RBLK * SSEG)   // 256
#define CVT_BLOCKS  1563            // 1.6M float4 / 1024
#define GRID_PREP   (BIN_BLOCKS + CVT_BLOCKS + 1)

typedef __attribute__((ext_vector_type(8))) short  short8;
typedef __attribute__((ext_vector_type(4))) short  short4_t;
typedef __attribute__((ext_vector_type(4))) float  float4_t;

__device__ inline short f2bf(float f) {
    union { float f; unsigned int u; } a;
    a.f = f;
    unsigned int r = a.u + 0x7FFFu + ((a.u >> 16) & 1u);  // RNE
    return (short)(r >> 16);
}
__device__ inline unsigned int pack2bf(float a, float b) {
    unsigned int lo = (unsigned short)f2bf(a);
    unsigned int hi = (unsigned short)f2bf(b);
    return lo | (hi << 16);
}
__device__ inline float bflo(unsigned int u) { return __uint_as_float(u << 16); }
__device__ inline float bfhi(unsigned int u) { return __uint_as_float(u & 0xFFFF0000u); }

// ---------------------------------------------------------------------------
// prep_kernel (fused, 1024 threads/block):
//   blocks [0,256):        bin edges by dst with LDS counters, no global
//                          atomics.  int4-vectorized dst stream (4 edges/
//                          thread/iter, 20 iters), prefetch next batch, src
//                          loaded only when any of the 4 match.
//   blocks [256,1819):     x fp32 -> xb bf16 packed.
//   block  1819:           W fp32 -> Wb bf16 packed.
// ---------------------------------------------------------------------------
__global__ __launch_bounds__(1024) void prep_kernel(
    const float* __restrict__ x, const int* __restrict__ e,
    const float* __restrict__ W,
    uint2* __restrict__ xb2, uint2* __restrict__ wb2,
    int* __restrict__ counts2, int* __restrict__ buckets)
{
    __shared__ int cnt[RSZ];
    const int bid = blockIdx.x;
    const int tid = threadIdx.x;

    if (bid < BIN_BLOCKS) {
        int r = bid & (RBLK - 1);
        int s = bid >> 5;                 // RBLK==32
        int base = r * RSZ;
        int rsz  = NNODES - base; if (rsz > RSZ) rsz = RSZ;

        for (int i = tid; i < RSZ; i += 1024) cnt[i] = 0;
        __syncthreads();

        const int4* dst4 = (const int4*)(e + NEDGES + s * (SEG_I4 * 4));
        const int4* src4 = (const int4*)(e + s * (SEG_I4 * 4));

        int i = tid;
        int4 d = (i < SEG_I4) ? dst4[i] : make_int4(-1, -1, -1, -1);
        while (i < SEG_I4) {
            int inx = i + 1024;
            int4 dn = d;
            if (inx < SEG_I4) dn = dst4[inx];            // prefetch next batch

            unsigned a0 = (unsigned)(d.x - base);
            unsigned a1 = (unsigned)(d.y - base);
            unsigned a2 = (unsigned)(d.z - base);
            unsigned a3 = (unsigned)(d.w - base);
            bool m0 = a0 < (unsigned)rsz;
            bool m1 = a1 < (unsigned)rsz;
            bool m2 = a2 < (unsigned)rsz;
            bool m3 = a3 < (unsigned)rsz;
            if (m0 | m1 | m2 | m3) {
                int4 sv = src4[i];
                if (m0) { int p = atomicAdd(&cnt[a0], 1); if (p < C0) buckets[d.x * CAPB + s * C0 + p] = sv.x; }
                if (m1) { int p = atomicAdd(&cnt[a1], 1); if (p < C0) buckets[d.y * CAPB + s * C0 + p] = sv.y; }
                if (m2) { int p = atomicAdd(&cnt[a2], 1); if (p < C0) buckets[d.z * CAPB + s * C0 + p] = sv.z; }
                if (m3) { int p = atomicAdd(&cnt[a3], 1); if (p < C0) buckets[d.w * CAPB + s * C0 + p] = sv.w; }
            }
            d = dn; i = inx;
        }
        __syncthreads();
        for (int i2 = tid; i2 < rsz; i2 += 1024) {
            int c = cnt[i2]; if (c > C0) c = C0;
            counts2[(base + i2) * SSEG + s] = c;
        }
    } else if (bid < BIN_BLOCKS + CVT_BLOCKS) {
        int i = (bid - BIN_BLOCKS) * 1024 + tid;        // float4 index
        if (i < 1600000) {
            float4 v = ((const float4*)x)[i];
            uint2 p; p.x = pack2bf(v.x, v.y); p.y = pack2bf(v.z, v.w);
            xb2[i] = p;
        }
    } else {
        for (int j = tid; j < 8192; j += 1024) {        // 32768 floats of W
            float4 v = ((const float4*)W)[j];
            uint2 p; p.x = pack2bf(v.x, v.y); p.y = pack2bf(v.z, v.w);
            wb2[j] = p;
        }
    }
}

// ---------------------------------------------------------------------------
// gather: one wave per node.  Compaction prologue (ballot+mbcnt+ds_permute)
// densifies the <=128 sub-slots into lanes [0,deg); main loop gathers two
// edges per 512B load round (half-wave each), idempotent-min tail clamp.
// ---------------------------------------------------------------------------
__global__ __launch_bounds__(256) void gather_min_bf16_kernel(
    const uint2* __restrict__ xb2, const int* __restrict__ counts2,
    const int* __restrict__ buckets, uint2* __restrict__ maxes2)
{
    int wave = (blockIdx.x * 256 + threadIdx.x) >> 6;
    int lane = threadIdx.x & 63;
    if (wave >= NNODES) return;
    int node = wave;

    // ---- compaction prologue ----
    int s0 = lane >> 4;                   // 0..3
    int j  = lane & 15;
    int c0 = counts2[node * SSEG + s0];
    int c1 = counts2[node * SSEG + 4 + s0];
    int idx0 = buckets[node * CAPB + lane];
    int idx1 = buckets[node * CAPB + 64 + lane];
    bool v0 = j < c0;
    bool v1 = j < c1;
    unsigned long long m0 = __ballot(v0);
    unsigned long long m1 = __ballot(v1);
    int p0 = __builtin_amdgcn_mbcnt_hi((unsigned)(m0 >> 32),
             __builtin_amdgcn_mbcnt_lo((unsigned)m0, 0));
    int popc0 = __popcll(m0);
    int p1 = popc0 + __builtin_amdgcn_mbcnt_hi((unsigned)(m1 >> 32),
                     __builtin_amdgcn_mbcnt_lo((unsigned)m1, 0));
    int deg = popc0 + __popcll(m1);
    int t0 = v0 ? p0 : 63;
    int t1 = v1 ? p1 : 63;
    int r0 = __builtin_amdgcn_ds_permute(t0 << 2, idx0);
    int r1 = __builtin_amdgcn_ds_permute(t1 << 2, idx1);
    int myidx = (lane < popc0) ? r0 : r1;

    int h  = lane >> 5;
    int cl = lane & 31;

    float4 m; m.x = 3.4e38f; m.y = 3.4e38f; m.z = 3.4e38f; m.w = 3.4e38f;
#pragma unroll 1
    for (int j0 = 0; j0 < deg; j0 += 16) {
        uint2 v[8];
#pragma unroll
        for (int u = 0; u < 8; ++u) {
            int jc = j0 + 2 * u + h;
            jc = jc < deg ? jc : deg - 1;
            int src = __shfl(myidx, jc);
            v[u] = xb2[(size_t)src * 32 + cl];
        }
#pragma unroll
        for (int u = 0; u < 8; ++u) {
            m.x = fminf(m.x, bflo(v[u].x));
            m.y = fminf(m.y, bfhi(v[u].x));
            m.z = fminf(m.z, bflo(v[u].y));
            m.w = fminf(m.w, bfhi(v[u].y));
        }
    }
    m.x = fminf(m.x, __shfl_xor(m.x, 32));
    m.y = fminf(m.y, __shfl_xor(m.y, 32));
    m.z = fminf(m.z, __shfl_xor(m.z, 32));
    m.w = fminf(m.w, __shfl_xor(m.w, 32));

    if (h == 0) {
        uint2 o;
        if (deg > 0) {
            uint2 xv = xb2[(size_t)node * 32 + cl];
            o.x = pack2bf(bflo(xv.x) - m.x, bfhi(xv.x) - m.y);
            o.y = pack2bf(bflo(xv.y) - m.z, bfhi(xv.y) - m.w);
        } else {
            o.x = 0u; o.y = 0u;
        }
        maxes2[(size_t)node * 32 + cl] = o;
    }
}

// ---------------------------------------------------------------------------
// Fallback kernels (small-ws path only).
// ---------------------------------------------------------------------------
__global__ __launch_bounds__(256) void fill_kernel(
    const int* __restrict__ e, int* __restrict__ counts, int* __restrict__ buckets)
{
    int i = blockIdx.x * 256 + threadIdx.x;
    if (i >= NEDGES) return;
    int src = e[i];
    int dst = e[NEDGES + i];
    int pos = atomicAdd(&counts[dst], 1);
    if (pos < 64) buckets[dst * 64 + pos] = src;
}

__global__ __launch_bounds__(256) void gather_min_fp32_kernel(
    const float* __restrict__ x, const int* __restrict__ counts,
    const int* __restrict__ buckets, unsigned int* __restrict__ maxes_u32)
{
    int wave = (blockIdx.x * 256 + threadIdx.x) >> 6;
    int lane = threadIdx.x & 63;
    if (wave >= NNODES) return;
    int node = wave;
    int deg  = counts[node];
    deg = deg > 64 ? 64 : deg;

    int myidx = (lane < deg) ? buckets[node * 64 + lane] : 0;
    int c = lane * 2;
    float2 m; m.x = 3.4e38f; m.y = 3.4e38f;
#pragma unroll 1
    for (int j0 = 0; j0 < deg; j0 += 8) {
        float2 v[8];
#pragma unroll
        for (int u = 0; u < 8; ++u) {
            int jc = j0 + u;
            jc = jc < deg ? jc : deg - 1;
            int src = __shfl(myidx, jc);
            v[u] = *(const float2*)(x + (size_t)src * WIDTH + c);
        }
#pragma unroll
        for (int u = 0; u < 8; ++u) {
            m.x = fminf(m.x, v[u].x);
            m.y = fminf(m.y, v[u].y);
        }
    }
    float2 o;
    if (deg > 0) {
        float2 xv = *(const float2*)(x + (size_t)node * WIDTH + c);
        o.x = xv.x - m.x;
        o.y = xv.y - m.y;
    } else { o.x = 0.f; o.y = 0.f; }
    maxes_u32[(size_t)node * 64 + lane] = pack2bf(o.x, o.y);
}

// ---------------------------------------------------------------------------
// fused GEMM: out = x + relu( [x, maxes] @ W^T + b ), bf16 MFMA, grid-stride
// over 16-row tiles (one tile per wave-pair).  FAST: bf16 Wb staging (plain
// copies) + bf16 xb A-frags.  !FAST: fp32 W/x with in-kernel conversion.
// ---------------------------------------------------------------------------
template<bool FAST>
__global__ __launch_bounds__(256, 2) void fused_gemm_kernel(
    const float* __restrict__ x, const short* __restrict__ xb,
    const short* __restrict__ maxes,
    const float* __restrict__ W, const short* __restrict__ Wb,
    const float* __restrict__ b, float* __restrict__ out)
{
    __shared__ short Wlds[WIDTH * WLDS_STRIDE];   // [n][k] bf16, padded

    const int t = threadIdx.x;

    if (FAST) {
#pragma unroll
        for (int i = 0; i < 32; ++i) {
            int idx8 = t + i * 256;            // short8 index, 8192 total
            int flat = idx8 << 3;
            short8 w = *(const short8*)(Wb + flat);
            int n = flat >> 8;
            int k = flat & 255;
            *(short4_t*)&Wlds[n * WLDS_STRIDE + k]     = *(short4_t*)&w;
            *(short4_t*)&Wlds[n * WLDS_STRIDE + k + 4] = *((short4_t*)&w + 1);
        }
    } else {
#pragma unroll
        for (int i = 0; i < 32; ++i) {
            int idx4 = t + i * 256;
            int flat = idx4 << 2;
            float4 w = *(const float4*)(W + flat);
            int n = flat >> 8;
            int k = flat & 255;
            short4_t s;
            s.x = f2bf(w.x); s.y = f2bf(w.y); s.z = f2bf(w.z); s.w = f2bf(w.w);
            *(short4_t*)&Wlds[n * WLDS_STRIDE + k] = s;
        }
    }
    __syncthreads();

    const int wave  = t >> 6;
    const int lane  = t & 63;
    const int lm    = lane & 15;
    const int quad  = lane >> 4;
    const int nhalf = wave & 1;
    const int wpair = wave >> 1;
    const int ncol_base = nhalf * 64;

    short8 bfrag[4][8];
#pragma unroll
    for (int nt = 0; nt < 4; ++nt) {
        int n = ncol_base + nt * 16 + lm;
#pragma unroll
        for (int kt = 0; kt < 8; ++kt) {
            int k = kt * 32 + quad * 8;
            bfrag[nt][kt] = *(const short8*)&Wlds[n * WLDS_STRIDE + k];
        }
    }

    const int stride = gridDim.x * 2;
#pragma unroll 1
    for (int tile = blockIdx.x * 2 + wpair; tile < NTILES; tile += stride) {
        int row = tile * 16 + lm;
        const float* xr  = x     + (size_t)row * WIDTH;
        const short* xbr = FAST ? (xb + (size_t)row * WIDTH) : nullptr;
        const short* mr  = maxes + (size_t)row * WIDTH;

        float4_t acc[4];
#pragma unroll
        for (int nt = 0; nt < 4; ++nt) { acc[nt].x = 0.f; acc[nt].y = 0.f; acc[nt].z = 0.f; acc[nt].w = 0.f; }

#pragma unroll
        for (int kt = 0; kt < 8; ++kt) {
            int k = kt * 32 + quad * 8;
            short8 afrag;
            if (k < WIDTH) {
                if (FAST) {
                    afrag = *(const short8*)(xbr + k);
                } else {
                    float4 v0 = *(const float4*)(xr + k);
                    float4 v1 = *(const float4*)(xr + k + 4);
                    afrag[0] = f2bf(v0.x); afrag[1] = f2bf(v0.y);
                    afrag[2] = f2bf(v0.z); afrag[3] = f2bf(v0.w);
                    afrag[4] = f2bf(v1.x); afrag[5] = f2bf(v1.y);
                    afrag[6] = f2bf(v1.z); afrag[7] = f2bf(v1.w);
                }
            } else {
                afrag = *(const short8*)(mr + (k - WIDTH));
            }
#pragma unroll
            for (int nt = 0; nt < 4; ++nt) {
                acc[nt] = __builtin_amdgcn_mfma_f32_16x16x32_bf16(
                    afrag, bfrag[nt][kt], acc[nt], 0, 0, 0);
            }
        }

#pragma unroll
        for (int nt = 0; nt < 4; ++nt) {
            int col = ncol_base + nt * 16 + lm;
            float bias = b[col];
#pragma unroll
            for (int r = 0; r < 4; ++r) {
                int orow = tile * 16 + quad * 4 + r;
                float v = acc[nt][r] + bias;
                v = v > 0.f ? v : 0.f;
                size_t off = (size_t)orow * WIDTH + col;
                out[off] = x[off] + v;
            }
        }
    }
}

extern "C" void kernel_launch(void* const* d_in, const int* in_sizes, int n_in,
                              void* d_out, int out_size, void* d_ws, size_t ws_size,
                              hipStream_t stream) {
    const float* x = (const float*)d_in[0];
    const int*   e = (const int*)  d_in[1];
    const float* W = (const float*)d_in[2];
    const float* b = (const float*)d_in[3];
    float* out = (float*)d_out;

    char* ws = (char*)d_ws;

    // main path workspace (byte offsets, all 16B-aligned)
    const size_t off_buckets = 1600512;                         // counts2: 50016*8*4
    const size_t off_maxes   = off_buckets + 25600000;          // buckets: 50000*128*4
    const size_t off_xb      = off_maxes + 12800000;
    const size_t off_wb      = off_xb + 12800000;
    const size_t need        = off_wb + 65536;                  // ~52.9 MB

    if (ws_size >= need) {
        int*          counts2 = (int*)ws;
        int*          buckets = (int*)(ws + off_buckets);
        unsigned int* maxes   = (unsigned int*)(ws + off_maxes);
        short*        xb      = (short*)(ws + off_xb);
        short*        wb      = (short*)(ws + off_wb);

        prep_kernel<<<GRID_PREP, 1024, 0, stream>>>(
            x, e, W, (uint2*)xb, (uint2*)wb, counts2, buckets);
        gather_min_bf16_kernel<<<(NNODES + 3) / 4, 256, 0, stream>>>(
            (const uint2*)xb, counts2, buckets, (uint2*)maxes);
        fused_gemm_kernel<true><<<512, 256, 0, stream>>>(
            x, xb, (const short*)maxes, W, wb, b, out);
    } else {
        // fallback: global-atomic fill + fp32 gather + fp32-W GEMM
        int*          counts  = (int*)ws;                            // 256 KB
        int*          buckets = (int*)(ws + 262144);                 // 12.8 MB
        unsigned int* maxes   = (unsigned int*)(ws + 262144 + 12800000);

        hipMemsetAsync(counts, 0, 262144, stream);
        fill_kernel<<<(NEDGES + 255) / 256, 256, 0, stream>>>(e, counts, buckets);
        gather_min_fp32_kernel<<<(NNODES + 3) / 4, 256, 0, stream>>>(
            x, counts, buckets, maxes);
        fused_gemm_kernel<false><<<512, 256, 0, stream>>>(
            x, nullptr, (const short*)maxes, W, nullptr, b, out);
    }
}